// Round 19
// baseline (61.364 us; speedup 1.0000x reference)
//
#include <hip/hip_runtime.h>
#include <hip/hip_bf16.h>
#include <math.h>

// Problem constants
#define NN 96
#define SS 4096
#define PP 4096
#define PH 1024
#define PHH 512
#define TP 3267            // TOTAL_PARAMS
#define KC_SPLIT 16
#define KCHUNK 256         // 4096 / 16
#define WSTR 68            // W LDS row stride (floats): 2-way banks (free)
#define ZSTR 100           // z LDS row stride (u32):    2-way banks (free)

typedef short short8 __attribute__((ext_vector_type(8)));   // MFMA A/B frag (8 bf16)
typedef float float4v __attribute__((ext_vector_type(4)));  // MFMA C/D frag
typedef unsigned uint4v __attribute__((ext_vector_type(4)));

__device__ __forceinline__ float stp(float x) {
    float sp = (x > 15.0f) ? x : log1pf(expf(x));
    return sp * (1.0f / 6.0f);
}

__device__ __forceinline__ float sin_w0(float x) {
    // sin(30*x) via Cody-Waite reduction to revolutions + v_sin_f32
    constexpr double Cd = 30.0 / 6.283185307179586476925286766559;
    constexpr float C_hi = (float)Cd;
    constexpr float C_lo = (float)(Cd - (double)C_hi);
    float t = x * C_hi;
    float k = rintf(t);
    float r = fmaf(x, C_hi, -k);
    r = fmaf(x, C_lo, r);
    return __builtin_amdgcn_sinf(r);
}

// bf16 round-to-nearest-even helpers (bit ops; values finite)
__device__ __forceinline__ unsigned short f2bf(float f) {
    unsigned u = __float_as_uint(f);
    unsigned r = u + 0x7fffu + ((u >> 16) & 1u);
    return (unsigned short)(r >> 16);
}
__device__ __forceinline__ float bf2f(unsigned short b) {
    return __uint_as_float(((unsigned)b) << 16);
}
// split v into hi+lo bf16, pack into u32 (hi in upper half)
__device__ __forceinline__ unsigned splitpack(float v) {
    unsigned short hb = f2bf(v);
    unsigned short lb = f2bf(v - bf2f(hb));
    return (((unsigned)hb) << 16) | (unsigned)lb;
}

// u32 bf16 bits via bit-op RNE (3 VALU, no NaN branch -- values finite)
__device__ __forceinline__ unsigned f2bfu(float f) {
    unsigned u = __float_as_uint(f);
    return (u + 0x7fffu + ((u >> 16) & 1u)) >> 16;
}

// pair (A,B) -> UH word (bf16(A) in lo16, bf16(B) in hi16) and UL word (lo
// residuals, same layout). Recovery uses the produced bits themselves.
#define PACKPAIR(A, B, UH, UL)                                          \
    {                                                                   \
        float _a = (A), _b = (B);                                       \
        unsigned _ha = f2bfu(_a), _hb = f2bfu(_b);                      \
        UH = _ha | (_hb << 16);                                         \
        float _ra = __uint_as_float(_ha << 16);                         \
        float _rb = __uint_as_float(_hb << 16);                         \
        UL = f2bfu(_a - _ra) | (f2bfu(_b - _rb) << 16);                 \
    }

__device__ __forceinline__ short8 u2s(uint4v u) {
    union { uint4v u; short8 s; } c; c.u = u; return c.s;
}

// ---------------- Kernel 1: build z, pack hi|lo bf16 into u32 plane ----------------
__global__ __launch_bounds__(256) void z_kernel(
    const float* __restrict__ loc, const float* __restrict__ log_scale,
    const float* __restrict__ h_loc, const float* __restrict__ h_ls,
    const float* __restrict__ hh_loc, const float* __restrict__ hh_ls,
    const float* __restrict__ eps, const float* __restrict__ h_eps,
    const float* __restrict__ hh_eps,
    const int* __restrict__ h_gi, const int* __restrict__ hh_gi,
    unsigned* __restrict__ z32)
{
    int t = blockIdx.x * 256 + threadIdx.x;      // t < 96*4096
    int p = t & (PP - 1);
    int n = t >> 12;
    int idx = n * PP + p;
    float s = loc[idx] + eps[idx] * stp(log_scale[idx]);
    int g  = h_gi[p];
    int gh = (n >> 4) * PH + g;
    float hs = h_loc[gh] + h_eps[gh] * stp(h_ls[gh]);
    int gg = hh_gi[p];
    float hhs = hh_loc[gg] + hh_eps[gg] * stp(hh_ls[gg]);
    z32[idx] = splitpack(s + hs + hhs);
}

// ---------------- Kernel 2: LDS-staged split-bf16 MFMA GEMM partials ----------------
#define MT(ACC, mt)                                                       \
    {                                                                     \
        short8 Ah, Al;                                                    \
        _Pragma("unroll")                                                 \
        for (int i = 0; i < 8; ++i) {                                     \
            int kl = ((i >> 2) << 4) + q4 + (i & 3);                      \
            unsigned u = zt[kl * ZSTR + (mt) * 16 + e];                   \
            Ah[i] = (short)(u >> 16);                                     \
            Al[i] = (short)(u & 0xffffu);                                 \
        }                                                                 \
        ACC = __builtin_amdgcn_mfma_f32_16x16x32_bf16(Ah, Bh, ACC, 0, 0, 0); \
        ACC = __builtin_amdgcn_mfma_f32_16x16x32_bf16(Al, Bh, ACC, 0, 0, 0); \
        ACC = __builtin_amdgcn_mfma_f32_16x16x32_bf16(Ah, Bl, ACC, 0, 0, 0); \
    }

__global__ __launch_bounds__(256, 3) void gemm_kernel(
    const float* __restrict__ Wm, const unsigned* __restrict__ z32,
    float* __restrict__ partials)
{
    int b  = blockIdx.x;
    int kc = b & 15;
    int jt = b >> 4;
    int tid = threadIdx.x;
    int wave = tid >> 6;
    int lane = tid & 63;
    int e  = lane & 15;
    int q4 = (lane >> 4) << 2;
    int j0 = (jt < 51) ? jt * 64 : (TP - 64);
    int j  = j0 + wave * 16 + e;
    int k0 = kc * KCHUNK;

    __shared__ float    wt[32 * WSTR];
    __shared__ unsigned zt[32 * ZSTR];

    float4v acc0 = {0,0,0,0}, acc1 = {0,0,0,0}, acc2 = {0,0,0,0};
    float4v acc3 = {0,0,0,0}, acc4 = {0,0,0,0}, acc5 = {0,0,0,0};

    int wrow = tid >> 3, wcol = tid & 7;
    int sm   = tid >> 1, skh = (tid & 1) << 4;

#pragma unroll 1
    for (int ks = 0; ks < KCHUNK / 32; ++ks) {
        int kb = k0 + ks * 32;

        float wv[8];
        const float* wsrc = Wm + (size_t)(kb + wrow) * TP + j0 + wcol;
#pragma unroll
        for (int u = 0; u < 8; ++u) wv[u] = wsrc[u * 8];
        unsigned zv[16];
        if (tid < 192) {
            const unsigned* zsrc = z32 + (size_t)sm * PP + kb + skh;
#pragma unroll
            for (int u = 0; u < 4; ++u)
                *(uint4*)(zv + u * 4) = *(const uint4*)(zsrc + u * 4);
        }

        __syncthreads();

#pragma unroll
        for (int u = 0; u < 8; ++u) wt[wrow * WSTR + wcol + u * 8] = wv[u];
        if (tid < 192) {
#pragma unroll
            for (int kk = 0; kk < 16; ++kk) zt[(skh + kk) * ZSTR + sm] = zv[kk];
        }

        __syncthreads();

        short8 Bh, Bl;
#pragma unroll
        for (int i = 0; i < 8; ++i) {
            int kl = ((i >> 2) << 4) + q4 + (i & 3);
            float w = wt[kl * WSTR + wave * 16 + e];
            unsigned short hb = f2bf(w);
            Bh[i] = (short)hb;
            Bl[i] = (short)f2bf(w - bf2f(hb));
        }

        MT(acc0, 0) MT(acc1, 1) MT(acc2, 2)
        MT(acc3, 3) MT(acc4, 4) MT(acc5, 5)
    }

    float* pp = partials + (size_t)(kc * NN) * TP + j;
#pragma unroll
    for (int r = 0; r < 4; ++r) pp[(size_t)(q4 + r) * TP]      = acc0[r];
#pragma unroll
    for (int r = 0; r < 4; ++r) pp[(size_t)(16 + q4 + r) * TP] = acc1[r];
#pragma unroll
    for (int r = 0; r < 4; ++r) pp[(size_t)(32 + q4 + r) * TP] = acc2[r];
#pragma unroll
    for (int r = 0; r < 4; ++r) pp[(size_t)(48 + q4 + r) * TP] = acc3[r];
#pragma unroll
    for (int r = 0; r < 4; ++r) pp[(size_t)(64 + q4 + r) * TP] = acc4[r];
#pragma unroll
    for (int r = 0; r < 4; ++r) pp[(size_t)(80 + q4 + r) * TP] = acc5[r];
}

// ---------------- Kernel 3: reduce partials + bias ----------------
__global__ __launch_bounds__(256) void reduce_kernel(
    const float* __restrict__ partials, const float* __restrict__ b_map,
    float* __restrict__ params)
{
    int t = blockIdx.x * 256 + threadIdx.x;
    if (t >= NN * TP) return;
    int j = t % TP;
    int n = t / TP;
    float a = b_map[j];
#pragma unroll
    for (int kc = 0; kc < KC_SPLIT; ++kc)
        a += partials[((size_t)(kc * NN + n)) * TP + j];
    params[(size_t)n * TP + j] = a;
}

// ---------------- Kernel 4: SIREN MLP, 1-tile body at 4 waves/SIMD ----------
// r18 insight: reported VGPR_Count excludes AGPRs (unified file). The 1-tile
// body's true footprint ~ 64 VGPR + ~20 AGPR = 84 << 128 = (256,4) cap, so
// 4 waves/SIMD is finally feasible (every 2-tile variant was ~104-140 and
// spilled at caps < 170). Grid 1536 = 96 n x 16 chunks = 4 blocks/CU..

#define PRELOAD_HALF(lp, off, BH, BL)                                   \
    {                                                                   \
        float _w[8];                                                    \
        _Pragma("unroll")                                               \
        for (int i = 0; i < 8; ++i) {                                   \
            int k = ((i >> 2) << 4) + q4 + (i & 3);                     \
            _w[i] = (lp)[32 + k * 32 + e + (off)];                      \
        }                                                               \
        uint4v _uh, _ul;                                                \
        PACKPAIR(_w[0], _w[1], _uh[0], _ul[0])                          \
        PACKPAIR(_w[2], _w[3], _uh[1], _ul[1])                          \
        PACKPAIR(_w[4], _w[5], _uh[2], _ul[2])                          \
        PACKPAIR(_w[6], _w[7], _uh[3], _ul[3])                          \
        BH = u2s(_uh);                                                  \
        BL = u2s(_ul);                                                  \
    }

// sin + hi/lo repack of 8 outputs (a0[0..3], a1[0..3]) -> HH/HL
#define SINPACK8(A0, A1, HH, HL)                                        \
    {                                                                   \
        float _s0 = sin_w0(A0[0]), _s1 = sin_w0(A0[1]);                 \
        float _s2 = sin_w0(A0[2]), _s3 = sin_w0(A0[3]);                 \
        float _s4 = sin_w0(A1[0]), _s5 = sin_w0(A1[1]);                 \
        float _s6 = sin_w0(A1[2]), _s7 = sin_w0(A1[3]);                 \
        uint4v _uh, _ul;                                                \
        PACKPAIR(_s0, _s1, _uh[0], _ul[0])                              \
        PACKPAIR(_s2, _s3, _uh[1], _ul[1])                              \
        PACKPAIR(_s4, _s5, _uh[2], _ul[2])                              \
        PACKPAIR(_s6, _s7, _uh[3], _ul[3])                              \
        HH = u2s(_uh);                                                  \
        HL = u2s(_ul);                                                  \
    }

// one hidden layer, single tile: 6 MFMAs + sin/repack
#define SLAYER(WH0, WL0, WH1, WL1, B0V, B1V)                            \
    {                                                                   \
        float4v a0 = (float4v){B0V.x, B0V.y, B0V.z, B0V.w};             \
        float4v a1 = (float4v){B1V.x, B1V.y, B1V.z, B1V.w};             \
        a0 = __builtin_amdgcn_mfma_f32_16x16x32_bf16(WH0, Hh0, a0, 0, 0, 0); \
        a1 = __builtin_amdgcn_mfma_f32_16x16x32_bf16(WH1, Hh0, a1, 0, 0, 0); \
        a0 = __builtin_amdgcn_mfma_f32_16x16x32_bf16(WH0, Hl0, a0, 0, 0, 0); \
        a1 = __builtin_amdgcn_mfma_f32_16x16x32_bf16(WH1, Hl0, a1, 0, 0, 0); \
        a0 = __builtin_amdgcn_mfma_f32_16x16x32_bf16(WL0, Hh0, a0, 0, 0, 0); \
        a1 = __builtin_amdgcn_mfma_f32_16x16x32_bf16(WL1, Hh0, a1, 0, 0, 0); \
        SINPACK8(a0, a1, Hh0, Hl0)                                      \
    }

// issue the two float4 x-loads for one 16-point tile (no packing)
#define XLOAD(M0, PA, PB)                                               \
    {                                                                   \
        const float* xr = x + ((size_t)(n * SS + (M0) + e)) * 32;       \
        PA = *(const float4*)(xr + q4);                                 \
        PB = *(const float4*)(xr + 16 + q4);                            \
    }

// pack prefetched x registers into H frags
#define XPACK(PA, PB, HH, HL)                                           \
    {                                                                   \
        uint4v _uh, _ul;                                                \
        PACKPAIR(PA.x, PA.y, _uh[0], _ul[0])                            \
        PACKPAIR(PA.z, PA.w, _uh[1], _ul[1])                            \
        PACKPAIR(PB.x, PB.y, _uh[2], _ul[2])                            \
        PACKPAIR(PB.z, PB.w, _uh[3], _ul[3])                            \
        HH = u2s(_uh);                                                  \
        HL = u2s(_ul);                                                  \
    }

__global__ __launch_bounds__(256, 4) void mlp_kernel(
    const float* __restrict__ x, const float* __restrict__ params,
    float* __restrict__ out)
{
    int b = blockIdx.x;
    int n = b >> 4;              // 16 chunks per n
    int chunk = b & 15;
    int tid = threadIdx.x;
    int wave = tid >> 6;
    int lane = tid & 63;
    int e  = lane & 15;          // pt within tile (and W-frag row e_out)
    int q4 = (lane >> 4) << 2;   // k-offset / output-e block

    const float* pr = params + (size_t)n * TP;

    // ---- preload weights as named W^T frags (A-operands), once per block ----
    short8 W0h0, W0l0, W0h1, W0l1;
    short8 W1h0, W1l0, W1h1, W1l1;
    short8 W2h0, W2l0, W2h1, W2l1;
    short8 WFh, WFl;
    float4 b0v, b1v, b2v, b0w, b1w, b2w, bFv;

    { const float* lp = pr;
      b0v = *(const float4*)(lp + q4); b0w = *(const float4*)(lp + 16 + q4);
      PRELOAD_HALF(lp, 0, W0h0, W0l0)  PRELOAD_HALF(lp, 16, W0h1, W0l1) }
    { const float* lp = pr + 1056;
      b1v = *(const float4*)(lp + q4); b1w = *(const float4*)(lp + 16 + q4);
      PRELOAD_HALF(lp, 0, W1h0, W1l0)  PRELOAD_HALF(lp, 16, W1h1, W1l1) }
    { const float* lp = pr + 2112;
      b2v = *(const float4*)(lp + q4); b2w = *(const float4*)(lp + 16 + q4);
      PRELOAD_HALF(lp, 0, W2h0, W2l0)  PRELOAD_HALF(lp, 16, W2h1, W2l1) }
    {   // final layer 32 -> 3 (rows e>=3 zero); bias per (q4+r)
        const float* lpf = pr + 3168;
        float4 bt = *(const float4*)(lpf + q4);   // lpf has 99 floats; q4<=12 in bounds
        bFv.x = (q4 + 0 < 3) ? bt.x : 0.0f;
        bFv.y = (q4 + 1 < 3) ? bt.y : 0.0f;
        bFv.z = (q4 + 2 < 3) ? bt.z : 0.0f;
        bFv.w = 0.0f;
        float _w[8];
#pragma unroll
        for (int i = 0; i < 8; ++i) {
            int k = ((i >> 2) << 4) + q4 + (i & 3);
            _w[i] = (e < 3) ? lpf[3 + k * 3 + e] : 0.0f;
        }
        uint4v _uh, _ul;
        PACKPAIR(_w[0], _w[1], _uh[0], _ul[0])
        PACKPAIR(_w[2], _w[3], _uh[1], _ul[1])
        PACKPAIR(_w[4], _w[5], _uh[2], _ul[2])
        PACKPAIR(_w[6], _w[7], _uh[3], _ul[3])
        WFh = u2s(_uh);
        WFl = u2s(_ul);
    }

    int p0 = chunk * 256 + wave * 64;   // 64 points per wave, 4 iterations

    // ---- prefetch x for iteration 0 ----
    float4 xa0, xb0;
    XLOAD(p0, xa0, xb0)

#pragma unroll 1
    for (int it = 0; it < 4; ++it) {
        int m0 = p0 + it * 16;

        // pack prefetched x, then immediately issue next iteration's loads
        short8 Hh0, Hl0;
        XPACK(xa0, xb0, Hh0, Hl0)
        int mn = (it < 3) ? (m0 + 16) : p0;   // wrap-safe dummy on last iter
        XLOAD(mn, xa0, xb0)

        SLAYER(W0h0, W0l0, W0h1, W0l1, b0v, b0w)
        SLAYER(W1h0, W1l0, W1h1, W1l1, b1v, b1w)
        SLAYER(W2h0, W2l0, W2h1, W2l1, b2v, b2w)

        // ---- final layer 32 -> 3 ----
        float4v fA = (float4v){bFv.x, bFv.y, bFv.z, bFv.w};
        fA = __builtin_amdgcn_mfma_f32_16x16x32_bf16(WFh, Hh0, fA, 0, 0, 0);
        fA = __builtin_amdgcn_mfma_f32_16x16x32_bf16(WFh, Hl0, fA, 0, 0, 0);
        fA = __builtin_amdgcn_mfma_f32_16x16x32_bf16(WFl, Hh0, fA, 0, 0, 0);

        if (q4 == 0) {                       // lanes 0..15: rows 0..2 = outputs
            float* op = out + ((size_t)n * SS + m0 + e) * 3;
            op[0] = fA[0]; op[1] = fA[1]; op[2] = fA[2];
        }
    }
}

extern "C" void kernel_launch(void* const* d_in, const int* in_sizes, int n_in,
                              void* d_out, int out_size, void* d_ws, size_t ws_size,
                              hipStream_t stream)
{
    const float* x        = (const float*)d_in[0];
    const float* loc      = (const float*)d_in[1];
    const float* log_sc   = (const float*)d_in[2];
    const float* h_loc    = (const float*)d_in[3];
    const float* h_ls     = (const float*)d_in[4];
    const float* hh_loc   = (const float*)d_in[5];
    const float* hh_ls    = (const float*)d_in[6];
    const float* eps      = (const float*)d_in[7];
    const float* h_eps    = (const float*)d_in[8];
    const float* hh_eps   = (const float*)d_in[9];
    const float* W_map    = (const float*)d_in[10];
    const float* b_map    = (const float*)d_in[11];
    const int*   h_gi     = (const int*)d_in[12];
    const int*   hh_gi    = (const int*)d_in[13];
    float* out = (float*)d_out;

    // workspace layout
    unsigned* z32  = (unsigned*)d_ws;                        // 96*4096 u32
    float* partials = (float*)(z32 + (size_t)NN * PP);       // 16*96*3267 f32
    float* params   = partials + (size_t)KC_SPLIT * NN * TP; // 96*3267 f32

    z_kernel<<<(NN * PP) / 256, 256, 0, stream>>>(
        loc, log_sc, h_loc, h_ls, hh_loc, hh_ls, eps, h_eps, hh_eps,
        h_gi, hh_gi, z32);

    gemm_kernel<<<52 * KC_SPLIT, 256, 0, stream>>>(W_map, z32, partials);

    reduce_kernel<<<(NN * TP + 255) / 256, 256, 0, stream>>>(partials, b_map, params);

    mlp_kernel<<<96 * 16, 256, 0, stream>>>(x, params, out);
}

// Round 20
// 59.857 us; speedup vs baseline: 1.0252x; 1.0252x over previous
//
#include <hip/hip_runtime.h>
#include <hip/hip_bf16.h>
#include <math.h>

// Problem constants
#define NN 96
#define SS 4096
#define PP 4096
#define PH 1024
#define PHH 512
#define TP 3267            // TOTAL_PARAMS
#define KC_SPLIT 16
#define KCHUNK 256         // 4096 / 16
#define WSTR 68            // W LDS row stride (floats): 2-way banks (free)
#define ZSTR 100           // z LDS row stride (u32):    2-way banks (free)

typedef short short8 __attribute__((ext_vector_type(8)));   // MFMA A/B frag (8 bf16)
typedef float float4v __attribute__((ext_vector_type(4)));  // MFMA C/D frag
typedef unsigned uint4v __attribute__((ext_vector_type(4)));

__device__ __forceinline__ float stp(float x) {
    float sp = (x > 15.0f) ? x : log1pf(expf(x));
    return sp * (1.0f / 6.0f);
}

// sin(30*x): r = 30x/(2pi) reduced to [-0.5,0.5], v_sin_f32 takes revolutions.
// 4-op variant (mul, rint, sub-fma, sin); dropping the C_lo compensation costs
// ~3e-6 rad absolute -- amplified ~20x downstream => ~1e-4, negligible vs the
// 0.029 absmax budget.
__device__ __forceinline__ float sin_w0(float x) {
    constexpr float C = (float)(30.0 / 6.283185307179586476925286766559);
    float t = x * C;
    float k = rintf(t);
    float r = fmaf(x, C, -k);
    return __builtin_amdgcn_sinf(r);
}

// bf16 round-to-nearest-even helpers (bit ops; values finite)
__device__ __forceinline__ unsigned short f2bf(float f) {
    unsigned u = __float_as_uint(f);
    unsigned r = u + 0x7fffu + ((u >> 16) & 1u);
    return (unsigned short)(r >> 16);
}
__device__ __forceinline__ float bf2f(unsigned short b) {
    return __uint_as_float(((unsigned)b) << 16);
}
// split v into hi+lo bf16, pack into u32 (hi in upper half)
__device__ __forceinline__ unsigned splitpack(float v) {
    unsigned short hb = f2bf(v);
    unsigned short lb = f2bf(v - bf2f(hb));
    return (((unsigned)hb) << 16) | (unsigned)lb;
}

// u32 bf16 bits via bit-op RNE (3 VALU, no NaN branch -- values finite)
__device__ __forceinline__ unsigned f2bfu(float f) {
    unsigned u = __float_as_uint(f);
    return (u + 0x7fffu + ((u >> 16) & 1u)) >> 16;
}

// pair (A,B) -> UH word (bf16(A) in lo16, bf16(B) in hi16) and UL word (lo
// residuals, same layout). Recovery uses the produced bits themselves.
#define PACKPAIR(A, B, UH, UL)                                          \
    {                                                                   \
        float _a = (A), _b = (B);                                       \
        unsigned _ha = f2bfu(_a), _hb = f2bfu(_b);                      \
        UH = _ha | (_hb << 16);                                         \
        float _ra = __uint_as_float(_ha << 16);                         \
        float _rb = __uint_as_float(_hb << 16);                         \
        UL = f2bfu(_a - _ra) | (f2bfu(_b - _rb) << 16);                 \
    }

__device__ __forceinline__ short8 u2s(uint4v u) {
    union { uint4v u; short8 s; } c; c.u = u; return c.s;
}

// ---------------- Kernel 1: build z, pack hi|lo bf16 into u32 plane ----------------
__global__ __launch_bounds__(256) void z_kernel(
    const float* __restrict__ loc, const float* __restrict__ log_scale,
    const float* __restrict__ h_loc, const float* __restrict__ h_ls,
    const float* __restrict__ hh_loc, const float* __restrict__ hh_ls,
    const float* __restrict__ eps, const float* __restrict__ h_eps,
    const float* __restrict__ hh_eps,
    const int* __restrict__ h_gi, const int* __restrict__ hh_gi,
    unsigned* __restrict__ z32)
{
    int t = blockIdx.x * 256 + threadIdx.x;      // t < 96*4096
    int p = t & (PP - 1);
    int n = t >> 12;
    int idx = n * PP + p;
    float s = loc[idx] + eps[idx] * stp(log_scale[idx]);
    int g  = h_gi[p];
    int gh = (n >> 4) * PH + g;
    float hs = h_loc[gh] + h_eps[gh] * stp(h_ls[gh]);
    int gg = hh_gi[p];
    float hhs = hh_loc[gg] + hh_eps[gg] * stp(hh_ls[gg]);
    z32[idx] = splitpack(s + hs + hhs);
}

// ---------------- Kernel 2: LDS-staged split-bf16 MFMA GEMM partials ----------------
#define MT(ACC, mt)                                                       \
    {                                                                     \
        short8 Ah, Al;                                                    \
        _Pragma("unroll")                                                 \
        for (int i = 0; i < 8; ++i) {                                     \
            int kl = ((i >> 2) << 4) + q4 + (i & 3);                      \
            unsigned u = zt[kl * ZSTR + (mt) * 16 + e];                   \
            Ah[i] = (short)(u >> 16);                                     \
            Al[i] = (short)(u & 0xffffu);                                 \
        }                                                                 \
        ACC = __builtin_amdgcn_mfma_f32_16x16x32_bf16(Ah, Bh, ACC, 0, 0, 0); \
        ACC = __builtin_amdgcn_mfma_f32_16x16x32_bf16(Al, Bh, ACC, 0, 0, 0); \
        ACC = __builtin_amdgcn_mfma_f32_16x16x32_bf16(Ah, Bl, ACC, 0, 0, 0); \
    }

__global__ __launch_bounds__(256, 3) void gemm_kernel(
    const float* __restrict__ Wm, const unsigned* __restrict__ z32,
    float* __restrict__ partials)
{
    int b  = blockIdx.x;
    int kc = b & 15;
    int jt = b >> 4;
    int tid = threadIdx.x;
    int wave = tid >> 6;
    int lane = tid & 63;
    int e  = lane & 15;
    int q4 = (lane >> 4) << 2;
    int j0 = (jt < 51) ? jt * 64 : (TP - 64);
    int j  = j0 + wave * 16 + e;
    int k0 = kc * KCHUNK;

    __shared__ float    wt[32 * WSTR];
    __shared__ unsigned zt[32 * ZSTR];

    float4v acc0 = {0,0,0,0}, acc1 = {0,0,0,0}, acc2 = {0,0,0,0};
    float4v acc3 = {0,0,0,0}, acc4 = {0,0,0,0}, acc5 = {0,0,0,0};

    int wrow = tid >> 3, wcol = tid & 7;
    int sm   = tid >> 1, skh = (tid & 1) << 4;

#pragma unroll 1
    for (int ks = 0; ks < KCHUNK / 32; ++ks) {
        int kb = k0 + ks * 32;

        float wv[8];
        const float* wsrc = Wm + (size_t)(kb + wrow) * TP + j0 + wcol;
#pragma unroll
        for (int u = 0; u < 8; ++u) wv[u] = wsrc[u * 8];
        unsigned zv[16];
        if (tid < 192) {
            const unsigned* zsrc = z32 + (size_t)sm * PP + kb + skh;
#pragma unroll
            for (int u = 0; u < 4; ++u)
                *(uint4*)(zv + u * 4) = *(const uint4*)(zsrc + u * 4);
        }

        __syncthreads();

#pragma unroll
        for (int u = 0; u < 8; ++u) wt[wrow * WSTR + wcol + u * 8] = wv[u];
        if (tid < 192) {
#pragma unroll
            for (int kk = 0; kk < 16; ++kk) zt[(skh + kk) * ZSTR + sm] = zv[kk];
        }

        __syncthreads();

        short8 Bh, Bl;
#pragma unroll
        for (int i = 0; i < 8; ++i) {
            int kl = ((i >> 2) << 4) + q4 + (i & 3);
            float w = wt[kl * WSTR + wave * 16 + e];
            unsigned short hb = f2bf(w);
            Bh[i] = (short)hb;
            Bl[i] = (short)f2bf(w - bf2f(hb));
        }

        MT(acc0, 0) MT(acc1, 1) MT(acc2, 2)
        MT(acc3, 3) MT(acc4, 4) MT(acc5, 5)
    }

    float* pp = partials + (size_t)(kc * NN) * TP + j;
#pragma unroll
    for (int r = 0; r < 4; ++r) pp[(size_t)(q4 + r) * TP]      = acc0[r];
#pragma unroll
    for (int r = 0; r < 4; ++r) pp[(size_t)(16 + q4 + r) * TP] = acc1[r];
#pragma unroll
    for (int r = 0; r < 4; ++r) pp[(size_t)(32 + q4 + r) * TP] = acc2[r];
#pragma unroll
    for (int r = 0; r < 4; ++r) pp[(size_t)(48 + q4 + r) * TP] = acc3[r];
#pragma unroll
    for (int r = 0; r < 4; ++r) pp[(size_t)(64 + q4 + r) * TP] = acc4[r];
#pragma unroll
    for (int r = 0; r < 4; ++r) pp[(size_t)(80 + q4 + r) * TP] = acc5[r];
}

// ---------------- Kernel 3: reduce partials + bias ----------------
__global__ __launch_bounds__(256) void reduce_kernel(
    const float* __restrict__ partials, const float* __restrict__ b_map,
    float* __restrict__ params)
{
    int t = blockIdx.x * 256 + threadIdx.x;
    if (t >= NN * TP) return;
    int j = t % TP;
    int n = t / TP;
    float a = b_map[j];
#pragma unroll
    for (int kc = 0; kc < KC_SPLIT; ++kc)
        a += partials[((size_t)(kc * NN + n)) * TP + j];
    params[(size_t)n * TP + j] = a;
}

// ---------------- Kernel 4: SIREN MLP (r17-best config) ----------
// 1-tile body, 768 blocks (96 n x 8 chunks = exactly 3/CU, one residency
// round -> minimal preamble amortization), 8 iterations/wave, x prefetched
// one iteration ahead, builtin bf16 packing. launch_bounds (256,3): the only
// non-spilling occupancy point (r10/r12/r16); (256,4)+1536 blocks regressed
// (r19: doubled preamble > TLP gain).

#define PRELOAD_HALF(lp, off, BH, BL)                                   \
    {                                                                   \
        float _w[8];                                                    \
        _Pragma("unroll")                                               \
        for (int i = 0; i < 8; ++i) {                                   \
            int k = ((i >> 2) << 4) + q4 + (i & 3);                     \
            _w[i] = (lp)[32 + k * 32 + e + (off)];                      \
        }                                                               \
        uint4v _uh, _ul;                                                \
        PACKPAIR(_w[0], _w[1], _uh[0], _ul[0])                          \
        PACKPAIR(_w[2], _w[3], _uh[1], _ul[1])                          \
        PACKPAIR(_w[4], _w[5], _uh[2], _ul[2])                          \
        PACKPAIR(_w[6], _w[7], _uh[3], _ul[3])                          \
        BH = u2s(_uh);                                                  \
        BL = u2s(_ul);                                                  \
    }

// sin + hi/lo repack of 8 outputs (a0[0..3], a1[0..3]) -> HH/HL
#define SINPACK8(A0, A1, HH, HL)                                        \
    {                                                                   \
        float _s0 = sin_w0(A0[0]), _s1 = sin_w0(A0[1]);                 \
        float _s2 = sin_w0(A0[2]), _s3 = sin_w0(A0[3]);                 \
        float _s4 = sin_w0(A1[0]), _s5 = sin_w0(A1[1]);                 \
        float _s6 = sin_w0(A1[2]), _s7 = sin_w0(A1[3]);                 \
        uint4v _uh, _ul;                                                \
        PACKPAIR(_s0, _s1, _uh[0], _ul[0])                              \
        PACKPAIR(_s2, _s3, _uh[1], _ul[1])                              \
        PACKPAIR(_s4, _s5, _uh[2], _ul[2])                              \
        PACKPAIR(_s6, _s7, _uh[3], _ul[3])                              \
        HH = u2s(_uh);                                                  \
        HL = u2s(_ul);                                                  \
    }

// one hidden layer, single tile: 6 MFMAs + sin/repack
#define SLAYER(WH0, WL0, WH1, WL1, B0V, B1V)                            \
    {                                                                   \
        float4v a0 = (float4v){B0V.x, B0V.y, B0V.z, B0V.w};             \
        float4v a1 = (float4v){B1V.x, B1V.y, B1V.z, B1V.w};             \
        a0 = __builtin_amdgcn_mfma_f32_16x16x32_bf16(WH0, Hh0, a0, 0, 0, 0); \
        a1 = __builtin_amdgcn_mfma_f32_16x16x32_bf16(WH1, Hh0, a1, 0, 0, 0); \
        a0 = __builtin_amdgcn_mfma_f32_16x16x32_bf16(WH0, Hl0, a0, 0, 0, 0); \
        a1 = __builtin_amdgcn_mfma_f32_16x16x32_bf16(WH1, Hl0, a1, 0, 0, 0); \
        a0 = __builtin_amdgcn_mfma_f32_16x16x32_bf16(WL0, Hh0, a0, 0, 0, 0); \
        a1 = __builtin_amdgcn_mfma_f32_16x16x32_bf16(WL1, Hh0, a1, 0, 0, 0); \
        SINPACK8(a0, a1, Hh0, Hl0)                                      \
    }

// issue the two float4 x-loads for one 16-point tile (no packing)
#define XLOAD(M0, PA, PB)                                               \
    {                                                                   \
        const float* xr = x + ((size_t)(n * SS + (M0) + e)) * 32;       \
        PA = *(const float4*)(xr + q4);                                 \
        PB = *(const float4*)(xr + 16 + q4);                            \
    }

// pack prefetched x registers into H frags
#define XPACK(PA, PB, HH, HL)                                           \
    {                                                                   \
        uint4v _uh, _ul;                                                \
        PACKPAIR(PA.x, PA.y, _uh[0], _ul[0])                            \
        PACKPAIR(PA.z, PA.w, _uh[1], _ul[1])                            \
        PACKPAIR(PB.x, PB.y, _uh[2], _ul[2])                            \
        PACKPAIR(PB.z, PB.w, _uh[3], _ul[3])                            \
        HH = u2s(_uh);                                                  \
        HL = u2s(_ul);                                                  \
    }

__global__ __launch_bounds__(256, 3) void mlp_kernel(
    const float* __restrict__ x, const float* __restrict__ params,
    float* __restrict__ out)
{
    int b = blockIdx.x;
    int n = b >> 3;              // 8 chunks per n
    int chunk = b & 7;
    int tid = threadIdx.x;
    int wave = tid >> 6;
    int lane = tid & 63;
    int e  = lane & 15;          // pt within tile (and W-frag row e_out)
    int q4 = (lane >> 4) << 2;   // k-offset / output-e block

    const float* pr = params + (size_t)n * TP;

    // ---- preload weights as named W^T frags (A-operands), once per block ----
    short8 W0h0, W0l0, W0h1, W0l1;
    short8 W1h0, W1l0, W1h1, W1l1;
    short8 W2h0, W2l0, W2h1, W2l1;
    short8 WFh, WFl;
    float4 b0v, b1v, b2v, b0w, b1w, b2w, bFv;

    { const float* lp = pr;
      b0v = *(const float4*)(lp + q4); b0w = *(const float4*)(lp + 16 + q4);
      PRELOAD_HALF(lp, 0, W0h0, W0l0)  PRELOAD_HALF(lp, 16, W0h1, W0l1) }
    { const float* lp = pr + 1056;
      b1v = *(const float4*)(lp + q4); b1w = *(const float4*)(lp + 16 + q4);
      PRELOAD_HALF(lp, 0, W1h0, W1l0)  PRELOAD_HALF(lp, 16, W1h1, W1l1) }
    { const float* lp = pr + 2112;
      b2v = *(const float4*)(lp + q4); b2w = *(const float4*)(lp + 16 + q4);
      PRELOAD_HALF(lp, 0, W2h0, W2l0)  PRELOAD_HALF(lp, 16, W2h1, W2l1) }
    {   // final layer 32 -> 3 (rows e>=3 zero); bias per (q4+r)
        const float* lpf = pr + 3168;
        float4 bt = *(const float4*)(lpf + q4);   // lpf has 99 floats; q4<=12 in bounds
        bFv.x = (q4 + 0 < 3) ? bt.x : 0.0f;
        bFv.y = (q4 + 1 < 3) ? bt.y : 0.0f;
        bFv.z = (q4 + 2 < 3) ? bt.z : 0.0f;
        bFv.w = 0.0f;
        float _w[8];
#pragma unroll
        for (int i = 0; i < 8; ++i) {
            int k = ((i >> 2) << 4) + q4 + (i & 3);
            _w[i] = (e < 3) ? lpf[3 + k * 3 + e] : 0.0f;
        }
        uint4v _uh, _ul;
        PACKPAIR(_w[0], _w[1], _uh[0], _ul[0])
        PACKPAIR(_w[2], _w[3], _uh[1], _ul[1])
        PACKPAIR(_w[4], _w[5], _uh[2], _ul[2])
        PACKPAIR(_w[6], _w[7], _uh[3], _ul[3])
        WFh = u2s(_uh);
        WFl = u2s(_ul);
    }

    int p0 = chunk * 512 + wave * 128;   // 128 points per wave, 8 iterations

    // ---- prefetch x for iteration 0 ----
    float4 xa0, xb0;
    XLOAD(p0, xa0, xb0)

#pragma unroll 1
    for (int it = 0; it < 8; ++it) {
        int m0 = p0 + it * 16;

        // pack prefetched x, then immediately issue next iteration's loads
        short8 Hh0, Hl0;
        XPACK(xa0, xb0, Hh0, Hl0)
        int mn = (it < 7) ? (m0 + 16) : p0;   // wrap-safe dummy on last iter
        XLOAD(mn, xa0, xb0)

        SLAYER(W0h0, W0l0, W0h1, W0l1, b0v, b0w)
        SLAYER(W1h0, W1l0, W1h1, W1l1, b1v, b1w)
        SLAYER(W2h0, W2l0, W2h1, W2l1, b2v, b2w)

        // ---- final layer 32 -> 3 ----
        float4v fA = (float4v){bFv.x, bFv.y, bFv.z, bFv.w};
        fA = __builtin_amdgcn_mfma_f32_16x16x32_bf16(WFh, Hh0, fA, 0, 0, 0);
        fA = __builtin_amdgcn_mfma_f32_16x16x32_bf16(WFh, Hl0, fA, 0, 0, 0);
        fA = __builtin_amdgcn_mfma_f32_16x16x32_bf16(WFl, Hh0, fA, 0, 0, 0);

        if (q4 == 0) {                       // lanes 0..15: rows 0..2 = outputs
            float* op = out + ((size_t)n * SS + m0 + e) * 3;
            op[0] = fA[0]; op[1] = fA[1]; op[2] = fA[2];
        }
    }
}

extern "C" void kernel_launch(void* const* d_in, const int* in_sizes, int n_in,
                              void* d_out, int out_size, void* d_ws, size_t ws_size,
                              hipStream_t stream)
{
    const float* x        = (const float*)d_in[0];
    const float* loc      = (const float*)d_in[1];
    const float* log_sc   = (const float*)d_in[2];
    const float* h_loc    = (const float*)d_in[3];
    const float* h_ls     = (const float*)d_in[4];
    const float* hh_loc   = (const float*)d_in[5];
    const float* hh_ls    = (const float*)d_in[6];
    const float* eps      = (const float*)d_in[7];
    const float* h_eps    = (const float*)d_in[8];
    const float* hh_eps   = (const float*)d_in[9];
    const float* W_map    = (const float*)d_in[10];
    const float* b_map    = (const float*)d_in[11];
    const int*   h_gi     = (const int*)d_in[12];
    const int*   hh_gi    = (const int*)d_in[13];
    float* out = (float*)d_out;

    // workspace layout
    unsigned* z32  = (unsigned*)d_ws;                        // 96*4096 u32
    float* partials = (float*)(z32 + (size_t)NN * PP);       // 16*96*3267 f32
    float* params   = partials + (size_t)KC_SPLIT * NN * TP; // 96*3267 f32

    z_kernel<<<(NN * PP) / 256, 256, 0, stream>>>(
        loc, log_sc, h_loc, h_ls, hh_loc, hh_ls, eps, h_eps, hh_eps,
        h_gi, hh_gi, z32);

    gemm_kernel<<<52 * KC_SPLIT, 256, 0, stream>>>(W_map, z32, partials);

    reduce_kernel<<<(NN * TP + 255) / 256, 256, 0, stream>>>(partials, b_map, params);

    mlp_kernel<<<96 * 8, 256, 0, stream>>>(x, params, out);
}

// Round 21
// 56.103 us; speedup vs baseline: 1.0938x; 1.0669x over previous
//
#include <hip/hip_runtime.h>
#include <hip/hip_bf16.h>
#include <math.h>

// Problem constants
#define NN 96
#define SS 4096
#define PP 4096
#define PH 1024
#define PHH 512
#define TP 3267            // TOTAL_PARAMS
#define KC_SPLIT 16
#define KCHUNK 256         // 4096 / 16
#define WSTR 68            // W LDS row stride (floats): 2-way banks (free)
#define ZSTR 100           // z LDS row stride (u32):    2-way banks (free)

typedef short short8 __attribute__((ext_vector_type(8)));   // MFMA A/B frag (8 bf16)
typedef float float4v __attribute__((ext_vector_type(4)));  // MFMA C/D frag
typedef unsigned uint4v __attribute__((ext_vector_type(4)));

__device__ __forceinline__ float stp(float x) {
    float sp = (x > 15.0f) ? x : log1pf(expf(x));
    return sp * (1.0f / 6.0f);
}

__device__ __forceinline__ float sin_w0(float x) {
    // sin(30*x) via Cody-Waite reduction to revolutions + v_sin_f32
    constexpr double Cd = 30.0 / 6.283185307179586476925286766559;
    constexpr float C_hi = (float)Cd;
    constexpr float C_lo = (float)(Cd - (double)C_hi);
    float t = x * C_hi;
    float k = rintf(t);
    float r = fmaf(x, C_hi, -k);
    r = fmaf(x, C_lo, r);
    return __builtin_amdgcn_sinf(r);
}

// bf16 round-to-nearest-even helpers (bit ops; values finite)
__device__ __forceinline__ unsigned short f2bf(float f) {
    unsigned u = __float_as_uint(f);
    unsigned r = u + 0x7fffu + ((u >> 16) & 1u);
    return (unsigned short)(r >> 16);
}
__device__ __forceinline__ float bf2f(unsigned short b) {
    return __uint_as_float(((unsigned)b) << 16);
}
// split v into hi+lo bf16, pack into u32 (hi in upper half)
__device__ __forceinline__ unsigned splitpack(float v) {
    unsigned short hb = f2bf(v);
    unsigned short lb = f2bf(v - bf2f(hb));
    return (((unsigned)hb) << 16) | (unsigned)lb;
}

// RNE f32->bf16 bits via the HIP builtin (compiler picks best lowering --
// round-14 lesson: hand-written cvt_pk asm had wrong half-order assumption).
__device__ __forceinline__ unsigned f2bfu(float f) {
    return (unsigned)__builtin_bit_cast(unsigned short, __float2bfloat16(f));
}

// pair (A,B) -> UH word (bf16(A) in lo16, bf16(B) in hi16) and UL word (lo
// residuals, same layout). Recovery uses the produced bits themselves, so
// correctness is lowering-independent.
#define PACKPAIR(A, B, UH, UL)                                          \
    {                                                                   \
        float _a = (A), _b = (B);                                       \
        unsigned _ha = f2bfu(_a), _hb = f2bfu(_b);                      \
        UH = _ha | (_hb << 16);                                         \
        float _ra = __uint_as_float(_ha << 16);                         \
        float _rb = __uint_as_float(_hb << 16);                         \
        UL = f2bfu(_a - _ra) | (f2bfu(_b - _rb) << 16);                 \
    }

__device__ __forceinline__ short8 u2s(uint4v u) {
    union { uint4v u; short8 s; } c; c.u = u; return c.s;
}

// ---------------- Kernel 1: build z, pack hi|lo bf16 into u32 plane ----------------
__global__ __launch_bounds__(256) void z_kernel(
    const float* __restrict__ loc, const float* __restrict__ log_scale,
    const float* __restrict__ h_loc, const float* __restrict__ h_ls,
    const float* __restrict__ hh_loc, const float* __restrict__ hh_ls,
    const float* __restrict__ eps, const float* __restrict__ h_eps,
    const float* __restrict__ hh_eps,
    const int* __restrict__ h_gi, const int* __restrict__ hh_gi,
    unsigned* __restrict__ z32)
{
    int t = blockIdx.x * 256 + threadIdx.x;      // t < 96*4096
    int p = t & (PP - 1);
    int n = t >> 12;
    int idx = n * PP + p;
    float s = loc[idx] + eps[idx] * stp(log_scale[idx]);
    int g  = h_gi[p];
    int gh = (n >> 4) * PH + g;
    float hs = h_loc[gh] + h_eps[gh] * stp(h_ls[gh]);
    int gg = hh_gi[p];
    float hhs = hh_loc[gg] + hh_eps[gg] * stp(hh_ls[gg]);
    z32[idx] = splitpack(s + hs + hhs);
}

// ---------------- Kernel 2: LDS-staged split-bf16 MFMA GEMM partials ----------------
#define MT(ACC, mt)                                                       \
    {                                                                     \
        short8 Ah, Al;                                                    \
        _Pragma("unroll")                                                 \
        for (int i = 0; i < 8; ++i) {                                     \
            int kl = ((i >> 2) << 4) + q4 + (i & 3);                      \
            unsigned u = zt[kl * ZSTR + (mt) * 16 + e];                   \
            Ah[i] = (short)(u >> 16);                                     \
            Al[i] = (short)(u & 0xffffu);                                 \
        }                                                                 \
        ACC = __builtin_amdgcn_mfma_f32_16x16x32_bf16(Ah, Bh, ACC, 0, 0, 0); \
        ACC = __builtin_amdgcn_mfma_f32_16x16x32_bf16(Al, Bh, ACC, 0, 0, 0); \
        ACC = __builtin_amdgcn_mfma_f32_16x16x32_bf16(Ah, Bl, ACC, 0, 0, 0); \
    }

__global__ __launch_bounds__(256, 3) void gemm_kernel(
    const float* __restrict__ Wm, const unsigned* __restrict__ z32,
    float* __restrict__ partials)
{
    int b  = blockIdx.x;
    int kc = b & 15;
    int jt = b >> 4;
    int tid = threadIdx.x;
    int wave = tid >> 6;
    int lane = tid & 63;
    int e  = lane & 15;
    int q4 = (lane >> 4) << 2;
    int j0 = (jt < 51) ? jt * 64 : (TP - 64);
    int j  = j0 + wave * 16 + e;
    int k0 = kc * KCHUNK;

    __shared__ float    wt[32 * WSTR];
    __shared__ unsigned zt[32 * ZSTR];

    float4v acc0 = {0,0,0,0}, acc1 = {0,0,0,0}, acc2 = {0,0,0,0};
    float4v acc3 = {0,0,0,0}, acc4 = {0,0,0,0}, acc5 = {0,0,0,0};

    int wrow = tid >> 3, wcol = tid & 7;
    int sm   = tid >> 1, skh = (tid & 1) << 4;

#pragma unroll 1
    for (int ks = 0; ks < KCHUNK / 32; ++ks) {
        int kb = k0 + ks * 32;

        float wv[8];
        const float* wsrc = Wm + (size_t)(kb + wrow) * TP + j0 + wcol;
#pragma unroll
        for (int u = 0; u < 8; ++u) wv[u] = wsrc[u * 8];
        unsigned zv[16];
        if (tid < 192) {
            const unsigned* zsrc = z32 + (size_t)sm * PP + kb + skh;
#pragma unroll
            for (int u = 0; u < 4; ++u)
                *(uint4*)(zv + u * 4) = *(const uint4*)(zsrc + u * 4);
        }

        __syncthreads();

#pragma unroll
        for (int u = 0; u < 8; ++u) wt[wrow * WSTR + wcol + u * 8] = wv[u];
        if (tid < 192) {
#pragma unroll
            for (int kk = 0; kk < 16; ++kk) zt[(skh + kk) * ZSTR + sm] = zv[kk];
        }

        __syncthreads();

        short8 Bh, Bl;
#pragma unroll
        for (int i = 0; i < 8; ++i) {
            int kl = ((i >> 2) << 4) + q4 + (i & 3);
            float w = wt[kl * WSTR + wave * 16 + e];
            unsigned short hb = f2bf(w);
            Bh[i] = (short)hb;
            Bl[i] = (short)f2bf(w - bf2f(hb));
        }

        MT(acc0, 0) MT(acc1, 1) MT(acc2, 2)
        MT(acc3, 3) MT(acc4, 4) MT(acc5, 5)
    }

    float* pp = partials + (size_t)(kc * NN) * TP + j;
#pragma unroll
    for (int r = 0; r < 4; ++r) pp[(size_t)(q4 + r) * TP]      = acc0[r];
#pragma unroll
    for (int r = 0; r < 4; ++r) pp[(size_t)(16 + q4 + r) * TP] = acc1[r];
#pragma unroll
    for (int r = 0; r < 4; ++r) pp[(size_t)(32 + q4 + r) * TP] = acc2[r];
#pragma unroll
    for (int r = 0; r < 4; ++r) pp[(size_t)(48 + q4 + r) * TP] = acc3[r];
#pragma unroll
    for (int r = 0; r < 4; ++r) pp[(size_t)(64 + q4 + r) * TP] = acc4[r];
#pragma unroll
    for (int r = 0; r < 4; ++r) pp[(size_t)(80 + q4 + r) * TP] = acc5[r];
}

// ---------------- Kernel 3: reduce partials + bias ----------------
__global__ __launch_bounds__(256) void reduce_kernel(
    const float* __restrict__ partials, const float* __restrict__ b_map,
    float* __restrict__ params)
{
    int t = blockIdx.x * 256 + threadIdx.x;
    if (t >= NN * TP) return;
    int j = t % TP;
    int n = t / TP;
    float a = b_map[j];
#pragma unroll
    for (int kc = 0; kc < KC_SPLIT; ++kc)
        a += partials[((size_t)(kc * NN + n)) * TP + j];
    params[(size_t)n * TP + j] = a;
}

// ---------------- Kernel 4: SIREN MLP (best-measured config, r17: 56.3 us) ----
// Swapped-operand MFMA (register-local inter-layer transpose, zero LDS);
// 2 independent 16-point tiles/wave; x prefetched one iteration ahead;
// builtin bf16 packing; 768 blocks (96 n x 8 chunks = exactly 3/CU, one
// residency round); launch_bounds (256,3): the only non-spilling occupancy
// point (r10/r12/r16 all spilled at lower caps; true footprint VGPR+AGPR).

#define PRELOAD_HALF(lp, off, BH, BL)                                   \
    {                                                                   \
        float _w[8];                                                    \
        _Pragma("unroll")                                               \
        for (int i = 0; i < 8; ++i) {                                   \
            int k = ((i >> 2) << 4) + q4 + (i & 3);                     \
            _w[i] = (lp)[32 + k * 32 + e + (off)];                      \
        }                                                               \
        uint4v _uh, _ul;                                                \
        PACKPAIR(_w[0], _w[1], _uh[0], _ul[0])                          \
        PACKPAIR(_w[2], _w[3], _uh[1], _ul[1])                          \
        PACKPAIR(_w[4], _w[5], _uh[2], _ul[2])                          \
        PACKPAIR(_w[6], _w[7], _uh[3], _ul[3])                          \
        BH = u2s(_uh);                                                  \
        BL = u2s(_ul);                                                  \
    }

// sin + hi/lo repack of one tile's 8 outputs (a0[0..3], a1[0..3]) -> HH/HL
#define SINPACK8(A0, A1, HH, HL)                                        \
    {                                                                   \
        float _s0 = sin_w0(A0[0]), _s1 = sin_w0(A0[1]);                 \
        float _s2 = sin_w0(A0[2]), _s3 = sin_w0(A0[3]);                 \
        float _s4 = sin_w0(A1[0]), _s5 = sin_w0(A1[1]);                 \
        float _s6 = sin_w0(A1[2]), _s7 = sin_w0(A1[3]);                 \
        uint4v _uh, _ul;                                                \
        PACKPAIR(_s0, _s1, _uh[0], _ul[0])                              \
        PACKPAIR(_s2, _s3, _uh[1], _ul[1])                              \
        PACKPAIR(_s4, _s5, _uh[2], _ul[2])                              \
        PACKPAIR(_s6, _s7, _uh[3], _ul[3])                              \
        HH = u2s(_uh);                                                  \
        HL = u2s(_ul);                                                  \
    }

// one hidden layer for BOTH independent tiles: 12 MFMAs + sin/repack
#define SLAYER2(WH0, WL0, WH1, WL1, B0V, B1V)                           \
    {                                                                   \
        float4v a0 = (float4v){B0V.x, B0V.y, B0V.z, B0V.w};             \
        float4v a1 = (float4v){B1V.x, B1V.y, B1V.z, B1V.w};             \
        float4v c0 = (float4v){B0V.x, B0V.y, B0V.z, B0V.w};             \
        float4v c1 = (float4v){B1V.x, B1V.y, B1V.z, B1V.w};             \
        a0 = __builtin_amdgcn_mfma_f32_16x16x32_bf16(WH0, Hh0, a0, 0, 0, 0); \
        c0 = __builtin_amdgcn_mfma_f32_16x16x32_bf16(WH0, Hh1, c0, 0, 0, 0); \
        a1 = __builtin_amdgcn_mfma_f32_16x16x32_bf16(WH1, Hh0, a1, 0, 0, 0); \
        c1 = __builtin_amdgcn_mfma_f32_16x16x32_bf16(WH1, Hh1, c1, 0, 0, 0); \
        a0 = __builtin_amdgcn_mfma_f32_16x16x32_bf16(WH0, Hl0, a0, 0, 0, 0); \
        c0 = __builtin_amdgcn_mfma_f32_16x16x32_bf16(WH0, Hl1, c0, 0, 0, 0); \
        a1 = __builtin_amdgcn_mfma_f32_16x16x32_bf16(WH1, Hl0, a1, 0, 0, 0); \
        c1 = __builtin_amdgcn_mfma_f32_16x16x32_bf16(WH1, Hl1, c1, 0, 0, 0); \
        a0 = __builtin_amdgcn_mfma_f32_16x16x32_bf16(WL0, Hh0, a0, 0, 0, 0); \
        c0 = __builtin_amdgcn_mfma_f32_16x16x32_bf16(WL0, Hh1, c0, 0, 0, 0); \
        a1 = __builtin_amdgcn_mfma_f32_16x16x32_bf16(WL1, Hh0, a1, 0, 0, 0); \
        c1 = __builtin_amdgcn_mfma_f32_16x16x32_bf16(WL1, Hh1, c1, 0, 0, 0); \
        SINPACK8(a0, a1, Hh0, Hl0)                                      \
        SINPACK8(c0, c1, Hh1, Hl1)                                      \
    }

// issue the two float4 x-loads for one 16-point tile (no packing)
#define XLOAD(M0, PA, PB)                                               \
    {                                                                   \
        const float* xr = x + ((size_t)(n * SS + (M0) + e)) * 32;       \
        PA = *(const float4*)(xr + q4);                                 \
        PB = *(const float4*)(xr + 16 + q4);                            \
    }

// pack prefetched x registers into H frags
#define XPACK(PA, PB, HH, HL)                                           \
    {                                                                   \
        uint4v _uh, _ul;                                                \
        PACKPAIR(PA.x, PA.y, _uh[0], _ul[0])                            \
        PACKPAIR(PA.z, PA.w, _uh[1], _ul[1])                            \
        PACKPAIR(PB.x, PB.y, _uh[2], _ul[2])                            \
        PACKPAIR(PB.z, PB.w, _uh[3], _ul[3])                            \
        HH = u2s(_uh);                                                  \
        HL = u2s(_ul);                                                  \
    }

__global__ __launch_bounds__(256, 3) void mlp_kernel(
    const float* __restrict__ x, const float* __restrict__ params,
    float* __restrict__ out)
{
    int b = blockIdx.x;
    int n = b >> 3;              // 8 chunks per n
    int chunk = b & 7;
    int tid = threadIdx.x;
    int wave = tid >> 6;
    int lane = tid & 63;
    int e  = lane & 15;          // pt within tile (and W-frag row e_out)
    int q4 = (lane >> 4) << 2;   // k-offset / output-e block

    const float* pr = params + (size_t)n * TP;

    // ---- preload weights as named W^T frags (A-operands), once per block ----
    short8 W0h0, W0l0, W0h1, W0l1;
    short8 W1h0, W1l0, W1h1, W1l1;
    short8 W2h0, W2l0, W2h1, W2l1;
    short8 WFh, WFl;
    float4 b0v, b1v, b2v, b0w, b1w, b2w, bFv;

    { const float* lp = pr;
      b0v = *(const float4*)(lp + q4); b0w = *(const float4*)(lp + 16 + q4);
      PRELOAD_HALF(lp, 0, W0h0, W0l0)  PRELOAD_HALF(lp, 16, W0h1, W0l1) }
    { const float* lp = pr + 1056;
      b1v = *(const float4*)(lp + q4); b1w = *(const float4*)(lp + 16 + q4);
      PRELOAD_HALF(lp, 0, W1h0, W1l0)  PRELOAD_HALF(lp, 16, W1h1, W1l1) }
    { const float* lp = pr + 2112;
      b2v = *(const float4*)(lp + q4); b2w = *(const float4*)(lp + 16 + q4);
      PRELOAD_HALF(lp, 0, W2h0, W2l0)  PRELOAD_HALF(lp, 16, W2h1, W2l1) }
    {   // final layer 32 -> 3 (rows e>=3 zero); bias per (q4+r)
        const float* lpf = pr + 3168;
        float4 bt = *(const float4*)(lpf + q4);   // lpf has 99 floats; q4<=12 in bounds
        bFv.x = (q4 + 0 < 3) ? bt.x : 0.0f;
        bFv.y = (q4 + 1 < 3) ? bt.y : 0.0f;
        bFv.z = (q4 + 2 < 3) ? bt.z : 0.0f;
        bFv.w = 0.0f;
        float _w[8];
#pragma unroll
        for (int i = 0; i < 8; ++i) {
            int k = ((i >> 2) << 4) + q4 + (i & 3);
            _w[i] = (e < 3) ? lpf[3 + k * 3 + e] : 0.0f;
        }
        uint4v _uh, _ul;
        PACKPAIR(_w[0], _w[1], _uh[0], _ul[0])
        PACKPAIR(_w[2], _w[3], _uh[1], _ul[1])
        PACKPAIR(_w[4], _w[5], _uh[2], _ul[2])
        PACKPAIR(_w[6], _w[7], _uh[3], _ul[3])
        WFh = u2s(_uh);
        WFl = u2s(_ul);
    }

    int p0 = chunk * 512 + wave * 128;   // 128 points per wave, 4 iterations

    // ---- prefetch x for iteration 0 ----
    float4 xa0, xb0, xa1, xb1;
    XLOAD(p0, xa0, xb0)
    XLOAD(p0 + 16, xa1, xb1)

#pragma unroll 1
    for (int it = 0; it < 4; ++it) {
        int m0 = p0 + it * 32;   // tile0: m0.., tile1: m0+16..

        // pack prefetched x, then immediately issue next iteration's loads
        short8 Hh0, Hl0, Hh1, Hl1;
        XPACK(xa0, xb0, Hh0, Hl0)
        XPACK(xa1, xb1, Hh1, Hl1)
        int mn = (it < 3) ? (m0 + 32) : p0;   // wrap-safe dummy on last iter
        XLOAD(mn, xa0, xb0)
        XLOAD(mn + 16, xa1, xb1)

        SLAYER2(W0h0, W0l0, W0h1, W0l1, b0v, b0w)
        SLAYER2(W1h0, W1l0, W1h1, W1l1, b1v, b1w)
        SLAYER2(W2h0, W2l0, W2h1, W2l1, b2v, b2w)

        // ---- final layer 32 -> 3, both tiles ----
        float4v fA = (float4v){bFv.x, bFv.y, bFv.z, bFv.w};
        float4v fB = (float4v){bFv.x, bFv.y, bFv.z, bFv.w};
        fA = __builtin_amdgcn_mfma_f32_16x16x32_bf16(WFh, Hh0, fA, 0, 0, 0);
        fB = __builtin_amdgcn_mfma_f32_16x16x32_bf16(WFh, Hh1, fB, 0, 0, 0);
        fA = __builtin_amdgcn_mfma_f32_16x16x32_bf16(WFh, Hl0, fA, 0, 0, 0);
        fB = __builtin_amdgcn_mfma_f32_16x16x32_bf16(WFh, Hl1, fB, 0, 0, 0);
        fA = __builtin_amdgcn_mfma_f32_16x16x32_bf16(WFl, Hh0, fA, 0, 0, 0);
        fB = __builtin_amdgcn_mfma_f32_16x16x32_bf16(WFl, Hh1, fB, 0, 0, 0);

        if (q4 == 0) {                       // lanes 0..15: rows 0..2 = outputs
            float* op0 = out + ((size_t)n * SS + m0 + e) * 3;
            op0[0] = fA[0]; op0[1] = fA[1]; op0[2] = fA[2];
            float* op1 = out + ((size_t)n * SS + m0 + 16 + e) * 3;
            op1[0] = fB[0]; op1[1] = fB[1]; op1[2] = fB[2];
        }
    }
}

extern "C" void kernel_launch(void* const* d_in, const int* in_sizes, int n_in,
                              void* d_out, int out_size, void* d_ws, size_t ws_size,
                              hipStream_t stream)
{
    const float* x        = (const float*)d_in[0];
    const float* loc      = (const float*)d_in[1];
    const float* log_sc   = (const float*)d_in[2];
    const float* h_loc    = (const float*)d_in[3];
    const float* h_ls     = (const float*)d_in[4];
    const float* hh_loc   = (const float*)d_in[5];
    const float* hh_ls    = (const float*)d_in[6];
    const float* eps      = (const float*)d_in[7];
    const float* h_eps    = (const float*)d_in[8];
    const float* hh_eps   = (const float*)d_in[9];
    const float* W_map    = (const float*)d_in[10];
    const float* b_map    = (const float*)d_in[11];
    const int*   h_gi     = (const int*)d_in[12];
    const int*   hh_gi    = (const int*)d_in[13];
    float* out = (float*)d_out;

    // workspace layout
    unsigned* z32  = (unsigned*)d_ws;                        // 96*4096 u32
    float* partials = (float*)(z32 + (size_t)NN * PP);       // 16*96*3267 f32
    float* params   = partials + (size_t)KC_SPLIT * NN * TP; // 96*3267 f32

    z_kernel<<<(NN * PP) / 256, 256, 0, stream>>>(
        loc, log_sc, h_loc, h_ls, hh_loc, hh_ls, eps, h_eps, hh_eps,
        h_gi, hh_gi, z32);

    gemm_kernel<<<52 * KC_SPLIT, 256, 0, stream>>>(W_map, z32, partials);

    reduce_kernel<<<(NN * TP + 255) / 256, 256, 0, stream>>>(partials, b_map, params);

    mlp_kernel<<<96 * 8, 256, 0, stream>>>(x, params, out);
}